// Round 3
// baseline (511.847 us; speedup 1.0000x reference)
//
#include <hip/hip_runtime.h>
#include <hip/hip_bf16.h>

// images: (B=32, C=3, H=1024, W=1024) fp32. GRID=4 -> region = 256x256.
// band = (b*3+c)*4 + gy : 256 rows x 1024 cols contiguous strip (1 MiB).
// Each band has 4 regions (gx = w/256).
// Stage 1: 6144 blocks; block = (band, sixteenth) covering 16 rows (64 KB).
//   8 blocks/CU resident -> full 32-wave occupancy; 3 even dispatch rounds.
//   Thread t loads float4 at column 4t of each row -> wave (t/64) == gx.
//   Wave shuffle-reduce -> partial[chunk*4 + gx]. No LDS, no atomics.
//   R3: plain (non-NT) loads — A/B vs R2's nontemporal hint.
// Stage 2: single block folds 24576 partials -> region means -> std(ddof=1) -> out.

typedef float v4f __attribute__((ext_vector_type(4)));

__global__ __launch_bounds__(256) void cc_stage1(const float* __restrict__ img,
                                                 float* __restrict__ partial) {
    const int chunk = blockIdx.x;        // 0..6143
    const int band  = chunk >> 4;        // 0..383
    const int six   = chunk & 15;        // 0..15  (16-row slice within band)
    const int t     = threadIdx.x;       // 0..255

    const v4f* base = (const v4f*)(img
                    + (size_t)band * (256u * 1024u)
                    + (size_t)six  * (16u * 1024u));

    v4f acc0 = {0.f, 0.f, 0.f, 0.f};
    v4f acc1 = {0.f, 0.f, 0.f, 0.f};
    #pragma unroll
    for (int r = 0; r < 16; r += 2) {
        v4f v0 = base[(r + 0) * 256 + t];   // contiguous 4 KB row per block-iter
        v4f v1 = base[(r + 1) * 256 + t];
        acc0 += v0;
        acc1 += v1;
    }
    v4f acc = acc0 + acc1;
    float s = (acc.x + acc.y) + (acc.z + acc.w);

    // wave64 reduce; wave index == region column gx
    #pragma unroll
    for (int off = 32; off > 0; off >>= 1)
        s += __shfl_down(s, off, 64);

    if ((t & 63) == 0)
        partial[chunk * 4 + (t >> 6)] = s;
}

__global__ __launch_bounds__(256) void cc_stage2(const float* __restrict__ partial,
                                                 float* __restrict__ out) {
    __shared__ float rmean[1536];   // region means, index = (b*3+c)*16 + gy*4 + gx
    __shared__ float stds[96];
    __shared__ float cons[32];
    const int t = threadIdx.x;

    for (int i = t; i < 1536; i += 256) {
        const int band = i >> 2, gx = i & 3;
        float s = 0.f;
        #pragma unroll
        for (int q = 0; q < 16; ++q)
            s += partial[(band * 16 + q) * 4 + gx];
        rmean[i] = s * (1.0f / 65536.0f);
    }
    __syncthreads();

    if (t < 96) {  // one (b,c) pair per thread
        float m = 0.f;
        #pragma unroll
        for (int j = 0; j < 16; ++j) m += rmean[t * 16 + j];
        m *= (1.0f / 16.0f);
        float v = 0.f;
        #pragma unroll
        for (int j = 0; j < 16; ++j) {
            const float d = rmean[t * 16 + j] - m;
            v += d * d;
        }
        stds[t] = sqrtf(v * (1.0f / 15.0f));   // ddof=1
    }
    __syncthreads();

    if (t < 32) {
        const float cs = (stds[t * 3] + stds[t * 3 + 1] + stds[t * 3 + 2]) * (1.0f / 3.0f);
        cons[t] = 1.0f / (1.0f + cs);
    }
    __syncthreads();

    if (t == 0) {
        float s = 0.f;
        #pragma unroll
        for (int j = 0; j < 32; ++j) s += cons[j];
        out[0] = s * (1.0f / 32.0f);
    }
}

extern "C" void kernel_launch(void* const* d_in, const int* in_sizes, int n_in,
                              void* d_out, int out_size, void* d_ws, size_t ws_size,
                              hipStream_t stream) {
    const float* img = (const float*)d_in[0];
    float* out       = (float*)d_out;
    float* partial   = (float*)d_ws;   // 6144*4 floats = 96 KB

    cc_stage1<<<6144, 256, 0, stream>>>(img, partial);
    cc_stage2<<<1, 256, 0, stream>>>(partial, out);
}

// Round 4
// 481.646 us; speedup vs baseline: 1.0627x; 1.0627x over previous
//
#include <hip/hip_runtime.h>
#include <hip/hip_bf16.h>

// images: (B=32, C=3, H=1024, W=1024) fp32. GRID=4 -> region = 256x256.
// band = (b*3+c)*4 + gy : 256 rows x 1024 cols contiguous strip (1 MiB).
// Each band has 4 regions (gx = w/256).
// Stage 1: 6144 blocks; block = (band, sixteenth) covering 16 rows (64 KB).
//   __launch_bounds__(256,8): force VGPR<=64 so 8 blocks/CU = 32 waves/CU.
//   NT float4 loads (R2 proved -20us vs plain: zero-reuse stream, bypass L2/L3).
//   Thread t loads float4 at column 4t of each row -> wave (t/64) == gx.
//   Wave shuffle-reduce -> partial[chunk*4 + gx]. No LDS, no atomics.
// Stage 2: single block folds 24576 partials -> region means -> std(ddof=1) -> out.

typedef float v4f __attribute__((ext_vector_type(4)));

__global__ __launch_bounds__(256, 8) void cc_stage1(const float* __restrict__ img,
                                                    float* __restrict__ partial) {
    const int chunk = blockIdx.x;        // 0..6143
    const int band  = chunk >> 4;        // 0..383
    const int six   = chunk & 15;        // 0..15  (16-row slice within band)
    const int t     = threadIdx.x;       // 0..255

    const v4f* base = (const v4f*)(img
                    + (size_t)band * (256u * 1024u)
                    + (size_t)six  * (16u * 1024u));

    v4f acc0 = {0.f, 0.f, 0.f, 0.f};
    v4f acc1 = {0.f, 0.f, 0.f, 0.f};
    #pragma unroll
    for (int r = 0; r < 16; r += 2) {
        v4f v0 = __builtin_nontemporal_load(&base[(r + 0) * 256 + t]);
        v4f v1 = __builtin_nontemporal_load(&base[(r + 1) * 256 + t]);
        acc0 += v0;
        acc1 += v1;
    }
    v4f acc = acc0 + acc1;
    float s = (acc.x + acc.y) + (acc.z + acc.w);

    // wave64 reduce; wave index == region column gx
    #pragma unroll
    for (int off = 32; off > 0; off >>= 1)
        s += __shfl_down(s, off, 64);

    if ((t & 63) == 0)
        partial[chunk * 4 + (t >> 6)] = s;
}

__global__ __launch_bounds__(256) void cc_stage2(const float* __restrict__ partial,
                                                 float* __restrict__ out) {
    __shared__ float rmean[1536];   // region means, index = (b*3+c)*16 + gy*4 + gx
    __shared__ float stds[96];
    __shared__ float cons[32];
    const int t = threadIdx.x;

    for (int i = t; i < 1536; i += 256) {
        const int band = i >> 2, gx = i & 3;
        float s = 0.f;
        #pragma unroll
        for (int q = 0; q < 16; ++q)
            s += partial[(band * 16 + q) * 4 + gx];
        rmean[i] = s * (1.0f / 65536.0f);
    }
    __syncthreads();

    if (t < 96) {  // one (b,c) pair per thread
        float m = 0.f;
        #pragma unroll
        for (int j = 0; j < 16; ++j) m += rmean[t * 16 + j];
        m *= (1.0f / 16.0f);
        float v = 0.f;
        #pragma unroll
        for (int j = 0; j < 16; ++j) {
            const float d = rmean[t * 16 + j] - m;
            v += d * d;
        }
        stds[t] = sqrtf(v * (1.0f / 15.0f));   // ddof=1
    }
    __syncthreads();

    if (t < 32) {
        const float cs = (stds[t * 3] + stds[t * 3 + 1] + stds[t * 3 + 2]) * (1.0f / 3.0f);
        cons[t] = 1.0f / (1.0f + cs);
    }
    __syncthreads();

    if (t == 0) {
        float s = 0.f;
        #pragma unroll
        for (int j = 0; j < 32; ++j) s += cons[j];
        out[0] = s * (1.0f / 32.0f);
    }
}

extern "C" void kernel_launch(void* const* d_in, const int* in_sizes, int n_in,
                              void* d_out, int out_size, void* d_ws, size_t ws_size,
                              hipStream_t stream) {
    const float* img = (const float*)d_in[0];
    float* out       = (float*)d_out;
    float* partial   = (float*)d_ws;   // 6144*4 floats = 96 KB

    cc_stage1<<<6144, 256, 0, stream>>>(img, partial);
    cc_stage2<<<1, 256, 0, stream>>>(partial, out);
}